// Round 1
// baseline (262.370 us; speedup 1.0000x reference)
//
#include <hip/hip_runtime.h>
#include <hip/hip_bf16.h>

#define H_  32
#define D_  4096
#define K_  128
#define V_  128
#define M_  8191     // prev cache length
#define MC_ 8192     // cache length after append

// ---------------------------------------------------------------------------
// Kernel A: q/k_new/v_new projections.  q[h,k] = sum_d x[d] * W[h,d,k]
// grid (8 d-chunks of 512, 32 heads, 3 projections), block 256.
// Partials atomically accumulated into ws (zeroed before launch).
// ---------------------------------------------------------------------------
__global__ void proj_kernel(const float* __restrict__ x,
                            const float* __restrict__ Wq,
                            const float* __restrict__ Wk,
                            const float* __restrict__ Wv,
                            float* __restrict__ qkv /* [3][H][K] */) {
    const int chunk = blockIdx.x;   // 0..7, 512 d each
    const int h     = blockIdx.y;
    const int proj  = blockIdx.z;
    const float* W  = (proj == 0) ? Wq : ((proj == 1) ? Wk : Wv);
    float* dst      = qkv + proj * (H_ * K_) + h * K_;

    __shared__ float xs[512];
    __shared__ float part[2][K_];

    const int t = threadIdx.x;      // 256
    xs[t]       = x[chunk * 512 + t];
    xs[t + 256] = x[chunk * 512 + t + 256];
    __syncthreads();

    const int k    = t & 127;
    const int half = t >> 7;
    const float* Wh = W + (size_t)h * D_ * K_ + (size_t)chunk * 512 * K_;

    float acc = 0.f;
    for (int dl = half; dl < 512; dl += 2)
        acc += xs[dl] * Wh[(size_t)dl * K_ + k];

    part[half][k] = acc;
    __syncthreads();
    if (t < K_) atomicAdd(&dst[t], part[0][t] + part[1][t]);
}

// ---------------------------------------------------------------------------
// Kernel B: fused K-cache copy + logits.  For each row m < M:
//   Kc[h,m,:] = prev_K[h,m,:];  logits[h,m] = dot(q[h], prev_K[h,m,:])
// grid (128 chunks of 64 rows, 32 heads), block 256 (4 waves).
// Each half-wave (32 lanes x float4) owns one row.
// ---------------------------------------------------------------------------
__global__ void logits_copyK_kernel(const float* __restrict__ prev_K,
                                    const float* __restrict__ qkv,
                                    float* __restrict__ Kc,
                                    float* __restrict__ lg) {
    const int chunk = blockIdx.x;
    const int h     = blockIdx.y;
    const int t     = threadIdx.x;
    const int lane  = t & 63;
    const int wave  = t >> 6;
    const int sub   = lane >> 5;    // which row of the pair
    const int cl    = lane & 31;    // column lane (float4)

    const float* q = qkv + h * K_;
    const float4 q4 = *(const float4*)&q[cl * 4];

    const float* Ksrc = prev_K + (size_t)h * M_ * K_;
    float*       Kd   = Kc     + (size_t)h * MC_ * K_;
    float*       L    = lg     + (size_t)h * MC_;

    for (int r = wave; r < 32; r += 4) {
        const int m = chunk * 64 + r * 2 + sub;
        if (m < M_) {
            const float4 v4 = *(const float4*)&Ksrc[(size_t)m * K_ + cl * 4];
            *(float4*)&Kd[(size_t)m * K_ + cl * 4] = v4;
            float p = v4.x * q4.x + v4.y * q4.y + v4.z * q4.z + v4.w * q4.w;
            #pragma unroll
            for (int off = 16; off > 0; off >>= 1) p += __shfl_down(p, off, 32);
            if (cl == 0) L[m] = p;
        }
    }
}

// ---------------------------------------------------------------------------
// Kernel C: per-head softmax over 8192 logits.  Also computes the appended
// row's logit q.k_new in LDS (avoids global RAW) and writes k_new/v_new into
// Kc/Vc row M.  grid 32, block 256; each thread holds 32 logits in registers.
// ---------------------------------------------------------------------------
__global__ void softmax_kernel(const float* __restrict__ qkv,
                               float* __restrict__ lg,
                               float* __restrict__ Kc,
                               float* __restrict__ Vc) {
    const int h = blockIdx.x;
    const int t = threadIdx.x;   // 256

    __shared__ float red[256];
    __shared__ float s_last, s_mx, s_inv;

    const float* q  = qkv + h * K_;
    const float* kn = qkv + H_ * K_ + h * K_;
    const float* vn = qkv + 2 * H_ * K_ + h * K_;
    float* L = lg + (size_t)h * MC_;

    // logit for the appended row + write k_new/v_new into the caches
    float p = 0.f;
    if (t < K_) {
        const float kv = kn[t];
        Kc[((size_t)h * MC_ + M_) * K_ + t] = kv;
        Vc[((size_t)h * MC_ + M_) * V_ + t] = vn[t];
        p = q[t] * kv;
    }
    red[t] = p;
    __syncthreads();
    for (int s = 128; s > 0; s >>= 1) {
        if (t < s) red[t] += red[t + s];
        __syncthreads();
    }
    if (t == 0) s_last = red[0];
    __syncthreads();

    // load all logits into registers (appended row from LDS, not global)
    float lv[32];
    #pragma unroll
    for (int j = 0; j < 32; ++j) {
        const int i = t + 256 * j;
        lv[j] = (i == M_) ? s_last : L[i];
    }

    // max reduce
    float mx = lv[0];
    #pragma unroll
    for (int j = 1; j < 32; ++j) mx = fmaxf(mx, lv[j]);
    red[t] = mx;
    __syncthreads();
    for (int s = 128; s > 0; s >>= 1) {
        if (t < s) red[t] = fmaxf(red[t], red[t + s]);
        __syncthreads();
    }
    if (t == 0) s_mx = red[0];
    __syncthreads();
    mx = s_mx;

    // exp + sum reduce (keep exps in registers; single global write pass)
    float e[32];
    float sum = 0.f;
    #pragma unroll
    for (int j = 0; j < 32; ++j) {
        e[j] = expf(lv[j] - mx);
        sum += e[j];
    }
    __syncthreads();
    red[t] = sum;
    __syncthreads();
    for (int s = 128; s > 0; s >>= 1) {
        if (t < s) red[t] += red[t + s];
        __syncthreads();
    }
    if (t == 0) s_inv = 1.f / red[0];
    __syncthreads();
    const float inv = s_inv;

    #pragma unroll
    for (int j = 0; j < 32; ++j) L[t + 256 * j] = e[j] * inv;
}

// ---------------------------------------------------------------------------
// Kernel D: fused V-cache copy + weighted sum.  o[h,v] += sum_m w[h,m]*V[h,m,v]
// grid (128 chunks of 64 rows, 32 heads), block 256.  Row M read back from Vc
// (written by kernel C).  Partials LDS-reduced then atomicAdd into o (zeroed).
// ---------------------------------------------------------------------------
__global__ void out_copyV_kernel(const float* __restrict__ prev_V,
                                 const float* __restrict__ lg,
                                 float* __restrict__ Vc,
                                 float* __restrict__ o /* [H][V] */) {
    const int chunk = blockIdx.x;
    const int h     = blockIdx.y;
    const int t     = threadIdx.x;
    const int lane  = t & 63;
    const int wave  = t >> 6;
    const int sub   = lane >> 5;
    const int cl    = lane & 31;

    const float* Vsrc = prev_V + (size_t)h * M_ * V_;
    float*       Vd   = Vc     + (size_t)h * MC_ * V_;
    const float* w    = lg     + (size_t)h * MC_;

    float4 acc = make_float4(0.f, 0.f, 0.f, 0.f);
    for (int r = wave; r < 32; r += 4) {
        const int m = chunk * 64 + r * 2 + sub;
        const float wm = w[m];
        float4 v4;
        if (m < M_) {
            v4 = *(const float4*)&Vsrc[(size_t)m * V_ + cl * 4];
            *(float4*)&Vd[(size_t)m * V_ + cl * 4] = v4;
        } else {
            v4 = *(const float4*)&Vd[(size_t)m * V_ + cl * 4];  // appended row
        }
        acc.x += wm * v4.x; acc.y += wm * v4.y;
        acc.z += wm * v4.z; acc.w += wm * v4.w;
    }

    __shared__ float lds[8][V_];
    const int slot = wave * 2 + sub;
    *(float4*)&lds[slot][cl * 4] = acc;
    __syncthreads();
    if (t < V_) {
        float s = 0.f;
        #pragma unroll
        for (int j = 0; j < 8; ++j) s += lds[j][t];
        atomicAdd(&o[h * V_ + t], s);
    }
}

// ---------------------------------------------------------------------------
// Kernel E: output projection.  y[d] += sum_v o[h,v] * Wo[h,v,d]
// grid (16 d-chunks of 256, 32 heads), block 256; atomicAdd into y (zeroed).
// ---------------------------------------------------------------------------
__global__ void yproj_kernel(const float* __restrict__ Wo,
                             const float* __restrict__ o,
                             float* __restrict__ y) {
    const int chunk = blockIdx.x;
    const int h     = blockIdx.y;
    const int t     = threadIdx.x;

    __shared__ float os[V_];
    if (t < V_) os[t] = o[h * V_ + t];
    __syncthreads();

    const int d = chunk * 256 + t;
    const float* Wh = Wo + (size_t)h * V_ * D_;
    float acc = 0.f;
    #pragma unroll 8
    for (int v = 0; v < V_; ++v) acc += os[v] * Wh[(size_t)v * D_ + d];
    atomicAdd(&y[d], acc);
}

// ---------------------------------------------------------------------------
extern "C" void kernel_launch(void* const* d_in, const int* in_sizes, int n_in,
                              void* d_out, int out_size, void* d_ws, size_t ws_size,
                              hipStream_t stream) {
    const float* x      = (const float*)d_in[0];
    const float* prev_K = (const float*)d_in[1];
    const float* prev_V = (const float*)d_in[2];
    const float* Wq     = (const float*)d_in[3];
    const float* Wk     = (const float*)d_in[4];
    const float* Wv     = (const float*)d_in[5];
    const float* Wo     = (const float*)d_in[6];

    float* out = (float*)d_out;
    float* y   = out;                                  // [D]
    float* Kc  = out + D_;                             // [H][MC][K]
    float* Vc  = Kc + (size_t)H_ * MC_ * K_;           // [H][MC][V]

    // workspace layout (floats): q[32][128], k_new, v_new, o, logits[32][8192]
    float* ws  = (float*)d_ws;
    float* qkv = ws;                  // 3 * 4096
    float* ov  = ws + 3 * H_ * K_;    // 4096
    float* lg  = ws + 4 * H_ * K_;    // 262144

    // zero the atomically-accumulated buffers (q/k/v/o and y)
    hipMemsetAsync(ws, 0, (size_t)4 * H_ * K_ * sizeof(float), stream);
    hipMemsetAsync(y, 0, (size_t)D_ * sizeof(float), stream);

    proj_kernel      <<<dim3(8, H_, 3),  256, 0, stream>>>(x, Wq, Wk, Wv, qkv);
    logits_copyK_kernel<<<dim3(128, H_), 256, 0, stream>>>(prev_K, qkv, Kc, lg);
    softmax_kernel   <<<H_,              256, 0, stream>>>(qkv, lg, Kc, Vc);
    out_copyV_kernel <<<dim3(128, H_),   256, 0, stream>>>(prev_V, lg, Vc, ov);
    yproj_kernel     <<<dim3(16, H_),    256, 0, stream>>>(Wo, ov, y);
}

// Round 2
// 185.349 us; speedup vs baseline: 1.4155x; 1.4155x over previous
//
#include <hip/hip_runtime.h>
#include <hip/hip_bf16.h>

#define H_  32
#define D_  4096
#define K_  128
#define V_  128
#define M_  8191     // prev cache length
#define MC_ 8192     // cache length after append

// ---------------------------------------------------------------------------
// Kernel A: q/k_new/v_new projections.  q[h,k] = sum_d x[d] * W[h,d,k]
// grid (16 d-chunks of 256, 32 heads, 3 projections), block 256.
// Each 32-lane group owns one W row per step (32 x float4 = 512 B coalesced),
// acc[k] float4 in registers; LDS reduce across the 8 groups; atomicAdd.
// ---------------------------------------------------------------------------
__global__ void proj_kernel(const float* __restrict__ x,
                            const float* __restrict__ Wq,
                            const float* __restrict__ Wk,
                            const float* __restrict__ Wv,
                            float* __restrict__ qkv /* [3][H][K] */) {
    const int chunk = blockIdx.x;   // 0..15, 256 d each
    const int h     = blockIdx.y;
    const int proj  = blockIdx.z;
    const float* W  = (proj == 0) ? Wq : ((proj == 1) ? Wk : Wv);
    float* dst      = qkv + proj * (H_ * K_) + h * K_;

    const int t   = threadIdx.x;    // 256
    const int grp = t >> 5;         // 0..7
    const int cl  = t & 31;         // float4 column lane

    __shared__ float xs[256];
    xs[t] = x[chunk * 256 + t];
    __syncthreads();

    const float* Wh = W + (size_t)h * D_ * K_ + (size_t)chunk * 256 * K_;

    float4 acc = make_float4(0.f, 0.f, 0.f, 0.f);
    #pragma unroll 4
    for (int r = grp; r < 256; r += 8) {
        const float4 v4 = *(const float4*)&Wh[(size_t)r * K_ + cl * 4];
        const float xd  = xs[r];
        acc.x += xd * v4.x; acc.y += xd * v4.y;
        acc.z += xd * v4.z; acc.w += xd * v4.w;
    }

    __shared__ float lds[8][K_];
    *(float4*)&lds[grp][cl * 4] = acc;
    __syncthreads();
    if (t < K_) {
        float s = 0.f;
        #pragma unroll
        for (int j = 0; j < 8; ++j) s += lds[j][t];
        atomicAdd(&dst[t], s);
    }
}

// ---------------------------------------------------------------------------
// Kernel B: fused K-cache copy + logits.  For each row m < M:
//   Kc[h,m,:] = prev_K[h,m,:];  logits[h,m] = dot(q[h], prev_K[h,m,:])
// grid (128 chunks of 64 rows, 32 heads), block 256 (4 waves).
// Each half-wave (32 lanes x float4) owns one row.
// ---------------------------------------------------------------------------
__global__ void logits_copyK_kernel(const float* __restrict__ prev_K,
                                    const float* __restrict__ qkv,
                                    float* __restrict__ Kc,
                                    float* __restrict__ lg) {
    const int chunk = blockIdx.x;
    const int h     = blockIdx.y;
    const int t     = threadIdx.x;
    const int lane  = t & 63;
    const int wave  = t >> 6;
    const int sub   = lane >> 5;    // which row of the pair
    const int cl    = lane & 31;    // column lane (float4)

    const float* q = qkv + h * K_;
    const float4 q4 = *(const float4*)&q[cl * 4];

    const float* Ksrc = prev_K + (size_t)h * M_ * K_;
    float*       Kd   = Kc     + (size_t)h * MC_ * K_;
    float*       L    = lg     + (size_t)h * MC_;

    for (int r = wave; r < 32; r += 4) {
        const int m = chunk * 64 + r * 2 + sub;
        if (m < M_) {
            const float4 v4 = *(const float4*)&Ksrc[(size_t)m * K_ + cl * 4];
            *(float4*)&Kd[(size_t)m * K_ + cl * 4] = v4;
            float p = v4.x * q4.x + v4.y * q4.y + v4.z * q4.z + v4.w * q4.w;
            #pragma unroll
            for (int off = 16; off > 0; off >>= 1) p += __shfl_down(p, off, 32);
            if (cl == 0) L[m] = p;
        }
    }
}

// ---------------------------------------------------------------------------
// Kernel C: per-head softmax over 8192 logits.  Also computes the appended
// row's logit q.k_new in LDS (avoids global RAW) and writes k_new/v_new into
// Kc/Vc row M.  grid 32, block 256; each thread holds 32 logits in registers.
// ---------------------------------------------------------------------------
__global__ void softmax_kernel(const float* __restrict__ qkv,
                               float* __restrict__ lg,
                               float* __restrict__ Kc,
                               float* __restrict__ Vc) {
    const int h = blockIdx.x;
    const int t = threadIdx.x;   // 256

    __shared__ float red[256];
    __shared__ float s_last, s_mx, s_inv;

    const float* q  = qkv + h * K_;
    const float* kn = qkv + H_ * K_ + h * K_;
    const float* vn = qkv + 2 * H_ * K_ + h * K_;
    float* L = lg + (size_t)h * MC_;

    // logit for the appended row + write k_new/v_new into the caches
    float p = 0.f;
    if (t < K_) {
        const float kv = kn[t];
        Kc[((size_t)h * MC_ + M_) * K_ + t] = kv;
        Vc[((size_t)h * MC_ + M_) * V_ + t] = vn[t];
        p = q[t] * kv;
    }
    red[t] = p;
    __syncthreads();
    for (int s = 128; s > 0; s >>= 1) {
        if (t < s) red[t] += red[t + s];
        __syncthreads();
    }
    if (t == 0) s_last = red[0];
    __syncthreads();

    // load all logits into registers (appended row from LDS, not global)
    float lv[32];
    #pragma unroll
    for (int j = 0; j < 32; ++j) {
        const int i = t + 256 * j;
        lv[j] = (i == M_) ? s_last : L[i];
    }

    // max reduce
    float mx = lv[0];
    #pragma unroll
    for (int j = 1; j < 32; ++j) mx = fmaxf(mx, lv[j]);
    red[t] = mx;
    __syncthreads();
    for (int s = 128; s > 0; s >>= 1) {
        if (t < s) red[t] = fmaxf(red[t], red[t + s]);
        __syncthreads();
    }
    if (t == 0) s_mx = red[0];
    __syncthreads();
    mx = s_mx;

    // exp + sum reduce (keep exps in registers; single global write pass)
    float e[32];
    float sum = 0.f;
    #pragma unroll
    for (int j = 0; j < 32; ++j) {
        e[j] = expf(lv[j] - mx);
        sum += e[j];
    }
    __syncthreads();
    red[t] = sum;
    __syncthreads();
    for (int s = 128; s > 0; s >>= 1) {
        if (t < s) red[t] += red[t + s];
        __syncthreads();
    }
    if (t == 0) s_inv = 1.f / red[0];
    __syncthreads();
    const float inv = s_inv;

    #pragma unroll
    for (int j = 0; j < 32; ++j) L[t + 256 * j] = e[j] * inv;
}

// ---------------------------------------------------------------------------
// Kernel D: fused V-cache copy + weighted sum.  o[h,v] += sum_m w[h,m]*V[h,m,v]
// grid (128 chunks of 64 rows, 32 heads), block 256.  Row M read back from Vc
// (written by kernel C).  Partials LDS-reduced then atomicAdd into o (zeroed).
// ---------------------------------------------------------------------------
__global__ void out_copyV_kernel(const float* __restrict__ prev_V,
                                 const float* __restrict__ lg,
                                 float* __restrict__ Vc,
                                 float* __restrict__ o /* [H][V] */) {
    const int chunk = blockIdx.x;
    const int h     = blockIdx.y;
    const int t     = threadIdx.x;
    const int lane  = t & 63;
    const int wave  = t >> 6;
    const int sub   = lane >> 5;
    const int cl    = lane & 31;

    const float* Vsrc = prev_V + (size_t)h * M_ * V_;
    float*       Vd   = Vc     + (size_t)h * MC_ * V_;
    const float* w    = lg     + (size_t)h * MC_;

    float4 acc = make_float4(0.f, 0.f, 0.f, 0.f);
    for (int r = wave; r < 32; r += 4) {
        const int m = chunk * 64 + r * 2 + sub;
        const float wm = w[m];
        float4 v4;
        if (m < M_) {
            v4 = *(const float4*)&Vsrc[(size_t)m * V_ + cl * 4];
            *(float4*)&Vd[(size_t)m * V_ + cl * 4] = v4;
        } else {
            v4 = *(const float4*)&Vd[(size_t)m * V_ + cl * 4];  // appended row
        }
        acc.x += wm * v4.x; acc.y += wm * v4.y;
        acc.z += wm * v4.z; acc.w += wm * v4.w;
    }

    __shared__ float lds[8][V_];
    const int slot = wave * 2 + sub;
    *(float4*)&lds[slot][cl * 4] = acc;
    __syncthreads();
    if (t < V_) {
        float s = 0.f;
        #pragma unroll
        for (int j = 0; j < 8; ++j) s += lds[j][t];
        atomicAdd(&o[h * V_ + t], s);
    }
}

// ---------------------------------------------------------------------------
// Kernel E: output projection.  y[d] += sum_v o[h,v] * Wo[h,v,d]
// grid (16 d-chunks of 256, 32 heads), block 256; atomicAdd into y (zeroed).
// ---------------------------------------------------------------------------
__global__ void yproj_kernel(const float* __restrict__ Wo,
                             const float* __restrict__ o,
                             float* __restrict__ y) {
    const int chunk = blockIdx.x;
    const int h     = blockIdx.y;
    const int t     = threadIdx.x;

    __shared__ float os[V_];
    if (t < V_) os[t] = o[h * V_ + t];
    __syncthreads();

    const int d = chunk * 256 + t;
    const float* Wh = Wo + (size_t)h * V_ * D_;
    float acc = 0.f;
    #pragma unroll 8
    for (int v = 0; v < V_; ++v) acc += os[v] * Wh[(size_t)v * D_ + d];
    atomicAdd(&y[d], acc);
}

// ---------------------------------------------------------------------------
extern "C" void kernel_launch(void* const* d_in, const int* in_sizes, int n_in,
                              void* d_out, int out_size, void* d_ws, size_t ws_size,
                              hipStream_t stream) {
    const float* x      = (const float*)d_in[0];
    const float* prev_K = (const float*)d_in[1];
    const float* prev_V = (const float*)d_in[2];
    const float* Wq     = (const float*)d_in[3];
    const float* Wk     = (const float*)d_in[4];
    const float* Wv     = (const float*)d_in[5];
    const float* Wo     = (const float*)d_in[6];

    float* out = (float*)d_out;
    float* y   = out;                                  // [D]
    float* Kc  = out + D_;                             // [H][MC][K]
    float* Vc  = Kc + (size_t)H_ * MC_ * K_;           // [H][MC][V]

    // workspace layout (floats): q[32][128], k_new, v_new, o, logits[32][8192]
    float* ws  = (float*)d_ws;
    float* qkv = ws;                  // 3 * 4096
    float* ov  = ws + 3 * H_ * K_;    // 4096
    float* lg  = ws + 4 * H_ * K_;    // 262144

    // zero the atomically-accumulated buffers (q/k/v/o and y)
    hipMemsetAsync(ws, 0, (size_t)4 * H_ * K_ * sizeof(float), stream);
    hipMemsetAsync(y, 0, (size_t)D_ * sizeof(float), stream);

    proj_kernel      <<<dim3(16, H_, 3), 256, 0, stream>>>(x, Wq, Wk, Wv, qkv);
    logits_copyK_kernel<<<dim3(128, H_), 256, 0, stream>>>(prev_K, qkv, Kc, lg);
    softmax_kernel   <<<H_,              256, 0, stream>>>(qkv, lg, Kc, Vc);
    out_copyV_kernel <<<dim3(128, H_),   256, 0, stream>>>(prev_V, lg, Vc, ov);
    yproj_kernel     <<<dim3(16, H_),    256, 0, stream>>>(Wo, ov, y);
}

// Round 3
// 183.277 us; speedup vs baseline: 1.4315x; 1.0113x over previous
//
#include <hip/hip_runtime.h>
#include <hip/hip_bf16.h>

#define H_  32
#define D_  4096
#define K_  128
#define V_  128
#define M_  8191     // prev cache length
#define MC_ 8192     // cache length after append

// ---------------------------------------------------------------------------
// Kernel A: q/k_new/v_new projections.  q[h,k] = sum_d x[d] * W[h,d,k]
// grid (32 d-chunks of 128, 32 heads, 3 projections), block 256.
// Each 32-lane group owns one W row per step (32 x float4 = 512 B coalesced),
// acc float4 in registers; LDS reduce across the 8 groups; atomicAdd.
// ---------------------------------------------------------------------------
__global__ void proj_kernel(const float* __restrict__ x,
                            const float* __restrict__ Wq,
                            const float* __restrict__ Wk,
                            const float* __restrict__ Wv,
                            float* __restrict__ qkv /* [3][H][K] */) {
    const int chunk = blockIdx.x;   // 0..31, 128 d each
    const int h     = blockIdx.y;
    const int proj  = blockIdx.z;
    const float* W  = (proj == 0) ? Wq : ((proj == 1) ? Wk : Wv);
    float* dst      = qkv + proj * (H_ * K_) + h * K_;

    const int t   = threadIdx.x;    // 256
    const int grp = t >> 5;         // 0..7
    const int cl  = t & 31;         // float4 column lane

    __shared__ float xs[128];
    if (t < 128) xs[t] = x[chunk * 128 + t];
    __syncthreads();

    const float* Wh = W + (size_t)h * D_ * K_ + (size_t)chunk * 128 * K_;

    float4 acc = make_float4(0.f, 0.f, 0.f, 0.f);
    #pragma unroll 4
    for (int r = grp; r < 128; r += 8) {
        const float4 v4 = *(const float4*)&Wh[(size_t)r * K_ + cl * 4];
        const float xd  = xs[r];
        acc.x += xd * v4.x; acc.y += xd * v4.y;
        acc.z += xd * v4.z; acc.w += xd * v4.w;
    }

    __shared__ float lds[8][K_];
    *(float4*)&lds[grp][cl * 4] = acc;
    __syncthreads();
    if (t < K_) {
        float s = 0.f;
        #pragma unroll
        for (int j = 0; j < 8; ++j) s += lds[j][t];
        atomicAdd(&dst[t], s);
    }
}

// ---------------------------------------------------------------------------
// Kernel B: fused K-cache copy + logits.  For each row m < M:
//   Kc[h,m,:] = prev_K[h,m,:];  logits[h,m] = dot(q[h], prev_K[h,m,:])
// grid (128 chunks of 64 rows, 32 heads), block 256 (8 half-wave groups).
// Per-lane dot partials go to LDS [64][33]; 64 threads do the final reduce.
// No per-row shuffles -> VMEM stream not stalled by DS waits.
// ---------------------------------------------------------------------------
__global__ void logits_copyK_kernel(const float* __restrict__ prev_K,
                                    const float* __restrict__ qkv,
                                    float* __restrict__ Kc,
                                    float* __restrict__ lg) {
    const int chunk = blockIdx.x;
    const int h     = blockIdx.y;
    const int t     = threadIdx.x;
    const int grp   = t >> 5;       // 0..7: half-wave group
    const int cl    = t & 31;       // float4 column lane

    const float* q = qkv + h * K_;
    const float4 q4 = *(const float4*)&q[cl * 4];

    const float* Ksrc = prev_K + (size_t)h * M_ * K_;
    float*       Kd   = Kc     + (size_t)h * MC_ * K_;
    float*       L    = lg     + (size_t)h * MC_;

    __shared__ float pbuf[64][33];

    #pragma unroll
    for (int r = 0; r < 8; ++r) {
        const int ml = r * 8 + grp;          // local row 0..63
        const int m  = chunk * 64 + ml;
        if (m < M_) {
            const float4 v4 = *(const float4*)&Ksrc[(size_t)m * K_ + cl * 4];
            *(float4*)&Kd[(size_t)m * K_ + cl * 4] = v4;
            pbuf[ml][cl] = v4.x * q4.x + v4.y * q4.y + v4.z * q4.z + v4.w * q4.w;
        }
    }
    __syncthreads();
    if (t < 64) {
        const int m = chunk * 64 + t;
        if (m < M_) {
            float s = 0.f;
            #pragma unroll
            for (int j = 0; j < 32; ++j) s += pbuf[t][j];
            L[m] = s;
        }
    }
}

// ---------------------------------------------------------------------------
// Kernel C: per-head softmax over 8192 logits.  Also computes the appended
// row's logit q.k_new in LDS (avoids global RAW) and writes k_new/v_new into
// Kc/Vc row M.  grid 32, block 256; each thread holds 32 logits in registers.
// ---------------------------------------------------------------------------
__global__ void softmax_kernel(const float* __restrict__ qkv,
                               float* __restrict__ lg,
                               float* __restrict__ Kc,
                               float* __restrict__ Vc) {
    const int h = blockIdx.x;
    const int t = threadIdx.x;   // 256

    __shared__ float red[256];
    __shared__ float s_last, s_mx, s_inv;

    const float* q  = qkv + h * K_;
    const float* kn = qkv + H_ * K_ + h * K_;
    const float* vn = qkv + 2 * H_ * K_ + h * K_;
    float* L = lg + (size_t)h * MC_;

    // logit for the appended row + write k_new/v_new into the caches
    float p = 0.f;
    if (t < K_) {
        const float kv = kn[t];
        Kc[((size_t)h * MC_ + M_) * K_ + t] = kv;
        Vc[((size_t)h * MC_ + M_) * V_ + t] = vn[t];
        p = q[t] * kv;
    }
    red[t] = p;
    __syncthreads();
    for (int s = 128; s > 0; s >>= 1) {
        if (t < s) red[t] += red[t + s];
        __syncthreads();
    }
    if (t == 0) s_last = red[0];
    __syncthreads();

    // load all logits into registers (appended row from LDS, not global)
    float lv[32];
    #pragma unroll
    for (int j = 0; j < 32; ++j) {
        const int i = t + 256 * j;
        lv[j] = (i == M_) ? s_last : L[i];
    }

    // max reduce
    float mx = lv[0];
    #pragma unroll
    for (int j = 1; j < 32; ++j) mx = fmaxf(mx, lv[j]);
    red[t] = mx;
    __syncthreads();
    for (int s = 128; s > 0; s >>= 1) {
        if (t < s) red[t] = fmaxf(red[t], red[t + s]);
        __syncthreads();
    }
    if (t == 0) s_mx = red[0];
    __syncthreads();
    mx = s_mx;

    // exp + sum reduce (keep exps in registers; single global write pass)
    float e[32];
    float sum = 0.f;
    #pragma unroll
    for (int j = 0; j < 32; ++j) {
        e[j] = expf(lv[j] - mx);
        sum += e[j];
    }
    __syncthreads();
    red[t] = sum;
    __syncthreads();
    for (int s = 128; s > 0; s >>= 1) {
        if (t < s) red[t] += red[t + s];
        __syncthreads();
    }
    if (t == 0) s_inv = 1.f / red[0];
    __syncthreads();
    const float inv = s_inv;

    #pragma unroll
    for (int j = 0; j < 32; ++j) L[t + 256 * j] = e[j] * inv;
}

// ---------------------------------------------------------------------------
// Kernel D: fused V-cache copy + weighted sum.  o[h,v] += sum_m w[h,m]*V[h,m,v]
// grid (128 chunks of 64 rows, 32 heads), block 256.  Row M read back from Vc
// (written by kernel C).  Partials LDS-reduced then atomicAdd into o (zeroed).
// ---------------------------------------------------------------------------
__global__ void out_copyV_kernel(const float* __restrict__ prev_V,
                                 const float* __restrict__ lg,
                                 float* __restrict__ Vc,
                                 float* __restrict__ o /* [H][V] */) {
    const int chunk = blockIdx.x;
    const int h     = blockIdx.y;
    const int t     = threadIdx.x;
    const int grp   = t >> 5;
    const int cl    = t & 31;

    const float* Vsrc = prev_V + (size_t)h * M_ * V_;
    float*       Vd   = Vc     + (size_t)h * MC_ * V_;
    const float* w    = lg     + (size_t)h * MC_;

    float4 acc = make_float4(0.f, 0.f, 0.f, 0.f);
    #pragma unroll
    for (int r = 0; r < 8; ++r) {
        const int m = chunk * 64 + r * 8 + grp;
        const float wm = w[m];
        float4 v4;
        if (m < M_) {
            v4 = *(const float4*)&Vsrc[(size_t)m * V_ + cl * 4];
            *(float4*)&Vd[(size_t)m * V_ + cl * 4] = v4;
        } else {
            v4 = *(const float4*)&Vd[(size_t)m * V_ + cl * 4];  // appended row
        }
        acc.x += wm * v4.x; acc.y += wm * v4.y;
        acc.z += wm * v4.z; acc.w += wm * v4.w;
    }

    __shared__ float lds[8][V_];
    *(float4*)&lds[grp][cl * 4] = acc;
    __syncthreads();
    if (t < V_) {
        float s = 0.f;
        #pragma unroll
        for (int j = 0; j < 8; ++j) s += lds[j][t];
        atomicAdd(&o[h * V_ + t], s);
    }
}

// ---------------------------------------------------------------------------
// Kernel E: output projection.  y[d] += sum_v o[h,v] * Wo[h,v,d]
// grid (16 d-chunks of 256, 32 heads), block 256; atomicAdd into y (zeroed).
// ---------------------------------------------------------------------------
__global__ void yproj_kernel(const float* __restrict__ Wo,
                             const float* __restrict__ o,
                             float* __restrict__ y) {
    const int chunk = blockIdx.x;
    const int h     = blockIdx.y;
    const int t     = threadIdx.x;

    __shared__ float os[V_];
    if (t < V_) os[t] = o[h * V_ + t];
    __syncthreads();

    const int d = chunk * 256 + t;
    const float* Wh = Wo + (size_t)h * V_ * D_;
    float acc = 0.f;
    #pragma unroll 8
    for (int v = 0; v < V_; ++v) acc += os[v] * Wh[(size_t)v * D_ + d];
    atomicAdd(&y[d], acc);
}

// ---------------------------------------------------------------------------
extern "C" void kernel_launch(void* const* d_in, const int* in_sizes, int n_in,
                              void* d_out, int out_size, void* d_ws, size_t ws_size,
                              hipStream_t stream) {
    const float* x      = (const float*)d_in[0];
    const float* prev_K = (const float*)d_in[1];
    const float* prev_V = (const float*)d_in[2];
    const float* Wq     = (const float*)d_in[3];
    const float* Wk     = (const float*)d_in[4];
    const float* Wv     = (const float*)d_in[5];
    const float* Wo     = (const float*)d_in[6];

    float* out = (float*)d_out;
    float* y   = out;                                  // [D]
    float* Kc  = out + D_;                             // [H][MC][K]
    float* Vc  = Kc + (size_t)H_ * MC_ * K_;           // [H][MC][V]

    // workspace layout (floats): q[32][128], k_new, v_new, o, logits[32][8192]
    float* ws  = (float*)d_ws;
    float* qkv = ws;                  // 3 * 4096
    float* ov  = ws + 3 * H_ * K_;    // 4096
    float* lg  = ws + 4 * H_ * K_;    // 262144

    // zero the atomically-accumulated buffers (q/k/v/o and y)
    hipMemsetAsync(ws, 0, (size_t)4 * H_ * K_ * sizeof(float), stream);
    hipMemsetAsync(y, 0, (size_t)D_ * sizeof(float), stream);

    proj_kernel      <<<dim3(32, H_, 3), 256, 0, stream>>>(x, Wq, Wk, Wv, qkv);
    logits_copyK_kernel<<<dim3(128, H_), 256, 0, stream>>>(prev_K, qkv, Kc, lg);
    softmax_kernel   <<<H_,              256, 0, stream>>>(qkv, lg, Kc, Vc);
    out_copyV_kernel <<<dim3(128, H_),   256, 0, stream>>>(prev_V, lg, Vc, ov);
    yproj_kernel     <<<dim3(16, H_),    256, 0, stream>>>(Wo, ov, y);
}

// Round 4
// 172.010 us; speedup vs baseline: 1.5253x; 1.0655x over previous
//
#include <hip/hip_runtime.h>
#include <hip/hip_bf16.h>

#define H_  32
#define D_  4096
#define K_  128
#define V_  128
#define M_  8191     // prev cache length
#define MC_ 8192     // cache length after append

typedef float f32x4 __attribute__((ext_vector_type(4)));

__device__ inline f32x4 ntload4(const float* p) {
    return __builtin_nontemporal_load((const f32x4*)p);
}
__device__ inline void ntstore4(float* p, f32x4 v) {
    __builtin_nontemporal_store(v, (f32x4*)p);
}

// sign-aware float atomic max (addr must be pre-initialized to 0xFFFFFFFF or
// a valid float). Positive values: signed-int max; negative: unsigned min.
__device__ inline void atomicMaxF(float* addr, float v) {
    if (v >= 0.f) atomicMax((int*)addr, __float_as_int(v));
    else          atomicMin((unsigned int*)addr, __float_as_uint(v));
}

// ---------------------------------------------------------------------------
// Kernel A: q/k_new/v_new projections.  q[h,k] = sum_d x[d] * W[h,d,k]
// grid (32 d-chunks of 128, 32 heads, 3 projections), block 256.
// ---------------------------------------------------------------------------
__global__ void proj_kernel(const float* __restrict__ x,
                            const float* __restrict__ Wq,
                            const float* __restrict__ Wk,
                            const float* __restrict__ Wv,
                            float* __restrict__ qkv /* [3][H][K] */) {
    const int chunk = blockIdx.x;   // 0..31, 128 d each
    const int h     = blockIdx.y;
    const int proj  = blockIdx.z;
    const float* W  = (proj == 0) ? Wq : ((proj == 1) ? Wk : Wv);
    float* dst      = qkv + proj * (H_ * K_) + h * K_;

    const int t   = threadIdx.x;    // 256
    const int grp = t >> 5;         // 0..7
    const int cl  = t & 31;         // float4 column lane

    __shared__ float xs[128];
    if (t < 128) xs[t] = x[chunk * 128 + t];
    __syncthreads();

    const float* Wh = W + (size_t)h * D_ * K_ + (size_t)chunk * 128 * K_;

    f32x4 acc = {0.f, 0.f, 0.f, 0.f};
    #pragma unroll 4
    for (int r = grp; r < 128; r += 8) {
        const f32x4 v4 = ntload4(&Wh[(size_t)r * K_ + cl * 4]);
        acc += xs[r] * v4;
    }

    __shared__ float lds[8][K_];
    *(f32x4*)&lds[grp][cl * 4] = acc;
    __syncthreads();
    if (t < K_) {
        float s = 0.f;
        #pragma unroll
        for (int j = 0; j < 8; ++j) s += lds[j][t];
        atomicAdd(&dst[t], s);
    }
}

// ---------------------------------------------------------------------------
// Kernel B: fused K-cache copy + logits + per-head running max.
// Handles ALL 8192 rows; row M sources k_new from ws (also writes Kc row M).
// grid (128 chunks of 64 rows, 32 heads), block 256 (8 half-wave groups).
// ---------------------------------------------------------------------------
__global__ void copyK_logits_kernel(const float* __restrict__ prev_K,
                                    const float* __restrict__ qkv,
                                    float* __restrict__ Kc,
                                    float* __restrict__ lg,
                                    float* __restrict__ mx /* [H] */) {
    const int chunk = blockIdx.x;
    const int h     = blockIdx.y;
    const int t     = threadIdx.x;
    const int grp   = t >> 5;       // 0..7: half-wave group
    const int cl    = t & 31;       // float4 column lane

    const float* q  = qkv + h * K_;
    const float* kn = qkv + H_ * K_ + h * K_;
    const f32x4 q4  = *(const f32x4*)&q[cl * 4];

    const float* Ksrc = prev_K + (size_t)h * M_ * K_;
    float*       Kd   = Kc     + (size_t)h * MC_ * K_;
    float*       L    = lg     + (size_t)h * MC_;

    __shared__ float pbuf[64][33];

    #pragma unroll
    for (int r = 0; r < 8; ++r) {
        const int ml = r * 8 + grp;          // local row 0..63
        const int m  = chunk * 64 + ml;
        const f32x4 v4 = (m == M_) ? *(const f32x4*)&kn[cl * 4]
                                   : ntload4(&Ksrc[(size_t)m * K_ + cl * 4]);
        ntstore4(&Kd[(size_t)m * K_ + cl * 4], v4);
        const f32x4 p4 = v4 * q4;
        pbuf[ml][cl] = p4.x + p4.y + p4.z + p4.w;
    }
    __syncthreads();

    __shared__ float rmax[64];
    if (t < 64) {
        float s = 0.f;
        #pragma unroll
        for (int j = 0; j < 32; ++j) s += pbuf[t][j];
        L[chunk * 64 + t] = s;
        rmax[t] = s;
    }
    __syncthreads();
    if (t == 0) {
        float mm = rmax[0];
        #pragma unroll
        for (int j = 1; j < 64; ++j) mm = fmaxf(mm, rmax[j]);
        atomicMaxF(&mx[h], mm);
    }
}

// ---------------------------------------------------------------------------
// Kernel D: fused V-cache copy + unnormalized exp-weighted sum + S accumulate.
//   o[h,v] += sum_m exp(l[m]-MX) * V[h,m,v];  S[h] += sum_m exp(l[m]-MX)
// Row M sources v_new from ws (also writes Vc row M).
// grid (128 chunks of 64 rows, 32 heads), block 256.
// ---------------------------------------------------------------------------
__global__ void copyV_out_kernel(const float* __restrict__ prev_V,
                                 const float* __restrict__ qkv,
                                 const float* __restrict__ lg,
                                 const float* __restrict__ mx,
                                 float* __restrict__ Vc,
                                 float* __restrict__ o /* [H][V] */,
                                 float* __restrict__ S /* [H] */) {
    const int chunk = blockIdx.x;
    const int h     = blockIdx.y;
    const int t     = threadIdx.x;
    const int grp   = t >> 5;
    const int cl    = t & 31;

    const float MX = mx[h];
    const float* vn   = qkv + 2 * H_ * K_ + h * K_;
    const float* Vsrc = prev_V + (size_t)h * M_ * V_;
    float*       Vd   = Vc     + (size_t)h * MC_ * V_;
    const float* L    = lg     + (size_t)h * MC_;

    f32x4 acc = {0.f, 0.f, 0.f, 0.f};
    #pragma unroll
    for (int r = 0; r < 8; ++r) {
        const int m = chunk * 64 + r * 8 + grp;
        const f32x4 v4 = (m == M_) ? *(const f32x4*)&vn[cl * 4]
                                   : ntload4(&Vsrc[(size_t)m * V_ + cl * 4]);
        ntstore4(&Vd[(size_t)m * V_ + cl * 4], v4);
        const float e = __expf(L[m] - MX);
        acc += e * v4;
    }

    __shared__ float lds[8][V_];
    *(f32x4*)&lds[grp][cl * 4] = acc;

    __shared__ float rsum[64];
    if (t < 64) rsum[t] = __expf(L[chunk * 64 + t] - MX);
    __syncthreads();

    if (t < V_) {
        float s = 0.f;
        #pragma unroll
        for (int j = 0; j < 8; ++j) s += lds[j][t];
        atomicAdd(&o[h * V_ + t], s);
    }
    if (t == 0) {
        float s = 0.f;
        #pragma unroll
        for (int j = 0; j < 64; ++j) s += rsum[j];
        atomicAdd(&S[h], s);
    }
}

// ---------------------------------------------------------------------------
// Kernel E: output projection with deferred softmax normalization.
//   y[d] += sum_v (o[h,v]/S[h]) * Wo[h,v,d]
// grid (16 d-chunks of 256, 32 heads), block 256; atomicAdd into y (zeroed).
// ---------------------------------------------------------------------------
__global__ void yproj_kernel(const float* __restrict__ Wo,
                             const float* __restrict__ o,
                             const float* __restrict__ S,
                             float* __restrict__ y) {
    const int chunk = blockIdx.x;
    const int h     = blockIdx.y;
    const int t     = threadIdx.x;

    __shared__ float os[V_];
    __shared__ float s_inv;
    if (t == 0) s_inv = 1.f / S[h];
    __syncthreads();
    if (t < V_) os[t] = o[h * V_ + t] * s_inv;
    __syncthreads();

    const int d = chunk * 256 + t;
    const float* Wh = Wo + (size_t)h * V_ * D_;
    float acc = 0.f;
    #pragma unroll 8
    for (int v = 0; v < V_; ++v)
        acc += os[v] * __builtin_nontemporal_load(&Wh[(size_t)v * D_ + d]);
    atomicAdd(&y[d], acc);
}

// ---------------------------------------------------------------------------
extern "C" void kernel_launch(void* const* d_in, const int* in_sizes, int n_in,
                              void* d_out, int out_size, void* d_ws, size_t ws_size,
                              hipStream_t stream) {
    const float* x      = (const float*)d_in[0];
    const float* prev_K = (const float*)d_in[1];
    const float* prev_V = (const float*)d_in[2];
    const float* Wq     = (const float*)d_in[3];
    const float* Wk     = (const float*)d_in[4];
    const float* Wv     = (const float*)d_in[5];
    const float* Wo     = (const float*)d_in[6];

    float* out = (float*)d_out;
    float* y   = out;                                  // [D]
    float* Kc  = out + D_;                             // [H][MC][K]
    float* Vc  = Kc + (size_t)H_ * MC_ * K_;           // [H][MC][V]

    // workspace (floats): qkv[3][H][K], o[H][V], S[H], mx[H], lg[H][MC]
    float* ws  = (float*)d_ws;
    float* qkv = ws;                                   // 12288
    float* ov  = qkv + 3 * H_ * K_;                    // 4096
    float* Sd  = ov + H_ * V_;                         // 32
    float* mxd = Sd + H_;                              // 32
    float* lg  = mxd + H_;                             // 262144

    // zero qkv/o/S and y; mx -> 0xFFFFFFFF (sign-aware atomicMaxF identity)
    hipMemsetAsync(ws, 0, (size_t)(3 * H_ * K_ + H_ * V_ + H_) * sizeof(float), stream);
    hipMemsetAsync(mxd, 0xFF, (size_t)H_ * sizeof(float), stream);
    hipMemsetAsync(y, 0, (size_t)D_ * sizeof(float), stream);

    proj_kernel       <<<dim3(32, H_, 3), 256, 0, stream>>>(x, Wq, Wk, Wv, qkv);
    copyK_logits_kernel<<<dim3(128, H_),  256, 0, stream>>>(prev_K, qkv, Kc, lg, mxd);
    copyV_out_kernel  <<<dim3(128, H_),   256, 0, stream>>>(prev_V, qkv, lg, mxd, Vc, ov, Sd);
    yproj_kernel      <<<dim3(16, H_),    256, 0, stream>>>(Wo, ov, Sd, y);
}

// Round 5
// 166.447 us; speedup vs baseline: 1.5763x; 1.0334x over previous
//
#include <hip/hip_runtime.h>
#include <hip/hip_bf16.h>
#include <math.h>

#define H_  32
#define D_  4096
#define K_  128
#define V_  128
#define M_  8191     // prev cache length
#define MC_ 8192     // cache length after append

typedef float f32x4 __attribute__((ext_vector_type(4)));

__device__ inline f32x4 ntload4(const float* p) {
    return __builtin_nontemporal_load((const f32x4*)p);
}
__device__ inline void ntstore4(float* p, f32x4 v) {
    __builtin_nontemporal_store(v, (f32x4*)p);
}

// sign-aware float atomic max (addr pre-initialized to -INF or valid float).
__device__ inline void atomicMaxF(float* addr, float v) {
    if (v >= 0.f) atomicMax((int*)addr, __float_as_int(v));
    else          atomicMin((unsigned int*)addr, __float_as_uint(v));
}

// ---------------------------------------------------------------------------
// Kernel A: q/k_new/v_new projections.  q[h,k] = sum_d x[d] * W[h,d,k]
// grid (32 d-chunks of 128, 32 heads, 3 projections), block 256.
// Also initializes mx[h] = -INF (proj completes before kernel B's atomics).
// ---------------------------------------------------------------------------
__global__ void proj_kernel(const float* __restrict__ x,
                            const float* __restrict__ Wq,
                            const float* __restrict__ Wk,
                            const float* __restrict__ Wv,
                            float* __restrict__ qkv /* [3][H][K] */,
                            float* __restrict__ mx  /* [H] */) {
    const int chunk = blockIdx.x;   // 0..31, 128 d each
    const int h     = blockIdx.y;
    const int proj  = blockIdx.z;
    const float* W  = (proj == 0) ? Wq : ((proj == 1) ? Wk : Wv);
    float* dst      = qkv + proj * (H_ * K_) + h * K_;

    const int t   = threadIdx.x;    // 256
    const int grp = t >> 5;         // 0..7
    const int cl  = t & 31;         // float4 column lane

    if (chunk == 0 && proj == 0 && t == 0) mx[h] = -INFINITY;

    __shared__ float xs[128];
    if (t < 128) xs[t] = x[chunk * 128 + t];
    __syncthreads();

    const float* Wh = W + (size_t)h * D_ * K_ + (size_t)chunk * 128 * K_;

    f32x4 acc = {0.f, 0.f, 0.f, 0.f};
    #pragma unroll 4
    for (int r = grp; r < 128; r += 8) {
        const f32x4 v4 = ntload4(&Wh[(size_t)r * K_ + cl * 4]);
        acc += xs[r] * v4;
    }

    __shared__ float lds[8][K_];
    *(f32x4*)&lds[grp][cl * 4] = acc;
    __syncthreads();
    if (t < K_) {
        float s = 0.f;
        #pragma unroll
        for (int j = 0; j < 8; ++j) s += lds[j][t];
        atomicAdd(&dst[t], s);
    }
}

// ---------------------------------------------------------------------------
// Kernel B: fused K-cache copy + logits + per-head running max.
// Handles ALL 8192 rows; row M sources k_new from ws (also writes Kc row M).
// Also zeroes o[h,:] and S[h] (B completes before kernel D's atomics).
// grid (128 chunks of 64 rows, 32 heads), block 256 (8 half-wave groups).
// ---------------------------------------------------------------------------
__global__ void copyK_logits_kernel(const float* __restrict__ prev_K,
                                    const float* __restrict__ qkv,
                                    float* __restrict__ Kc,
                                    float* __restrict__ lg,
                                    float* __restrict__ mx /* [H] */,
                                    float* __restrict__ o  /* [H][V] */,
                                    float* __restrict__ S  /* [H] */) {
    const int chunk = blockIdx.x;
    const int h     = blockIdx.y;
    const int t     = threadIdx.x;
    const int grp   = t >> 5;       // 0..7: half-wave group
    const int cl    = t & 31;       // float4 column lane

    if (chunk == 0) {
        if (t < V_) o[h * V_ + t] = 0.f;
        if (t == 0) S[h] = 0.f;
    }

    const float* q  = qkv + h * K_;
    const float* kn = qkv + H_ * K_ + h * K_;
    const f32x4 q4  = *(const f32x4*)&q[cl * 4];

    const float* Ksrc = prev_K + (size_t)h * M_ * K_;
    float*       Kd   = Kc     + (size_t)h * MC_ * K_;
    float*       L    = lg     + (size_t)h * MC_;

    __shared__ float pbuf[64][33];

    #pragma unroll
    for (int r = 0; r < 8; ++r) {
        const int ml = r * 8 + grp;          // local row 0..63
        const int m  = chunk * 64 + ml;
        const f32x4 v4 = (m == M_) ? *(const f32x4*)&kn[cl * 4]
                                   : ntload4(&Ksrc[(size_t)m * K_ + cl * 4]);
        ntstore4(&Kd[(size_t)m * K_ + cl * 4], v4);
        const f32x4 p4 = v4 * q4;
        pbuf[ml][cl] = p4.x + p4.y + p4.z + p4.w;
    }
    __syncthreads();

    __shared__ float rmax[64];
    if (t < 64) {
        float s = 0.f;
        #pragma unroll
        for (int j = 0; j < 32; ++j) s += pbuf[t][j];
        L[chunk * 64 + t] = s;
        rmax[t] = s;
    }
    __syncthreads();
    if (t == 0) {
        float mm = rmax[0];
        #pragma unroll
        for (int j = 1; j < 64; ++j) mm = fmaxf(mm, rmax[j]);
        atomicMaxF(&mx[h], mm);
    }
}

// ---------------------------------------------------------------------------
// Kernel D: fused V-cache copy + unnormalized exp-weighted sum + S accumulate.
//   o[h,v] += sum_m exp(l[m]-MX) * V[h,m,v];  S[h] += sum_m exp(l[m]-MX)
// Row M sources v_new from ws (also writes Vc row M).
// Also zeroes y (D completes before kernel E's atomics).
// grid (128 chunks of 64 rows, 32 heads), block 256.
// ---------------------------------------------------------------------------
__global__ void copyV_out_kernel(const float* __restrict__ prev_V,
                                 const float* __restrict__ qkv,
                                 const float* __restrict__ lg,
                                 const float* __restrict__ mx,
                                 float* __restrict__ Vc,
                                 float* __restrict__ o /* [H][V] */,
                                 float* __restrict__ S /* [H] */,
                                 float* __restrict__ y /* [D] */) {
    const int chunk = blockIdx.x;
    const int h     = blockIdx.y;
    const int t     = threadIdx.x;
    const int grp   = t >> 5;
    const int cl    = t & 31;

    if (chunk == 0 && t < 128) y[h * 128 + t] = 0.f;

    const float MX = mx[h];
    const float* vn   = qkv + 2 * H_ * K_ + h * K_;
    const float* Vsrc = prev_V + (size_t)h * M_ * V_;
    float*       Vd   = Vc     + (size_t)h * MC_ * V_;
    const float* L    = lg     + (size_t)h * MC_;

    f32x4 acc = {0.f, 0.f, 0.f, 0.f};
    #pragma unroll
    for (int r = 0; r < 8; ++r) {
        const int m = chunk * 64 + r * 8 + grp;
        const f32x4 v4 = (m == M_) ? *(const f32x4*)&vn[cl * 4]
                                   : ntload4(&Vsrc[(size_t)m * V_ + cl * 4]);
        ntstore4(&Vd[(size_t)m * V_ + cl * 4], v4);
        const float e = __expf(L[m] - MX);
        acc += e * v4;
    }

    __shared__ float lds[8][V_];
    *(f32x4*)&lds[grp][cl * 4] = acc;

    __shared__ float rsum[64];
    if (t < 64) rsum[t] = __expf(L[chunk * 64 + t] - MX);
    __syncthreads();

    if (t < V_) {
        float s = 0.f;
        #pragma unroll
        for (int j = 0; j < 8; ++j) s += lds[j][t];
        atomicAdd(&o[h * V_ + t], s);
    }
    if (t == 0) {
        float s = 0.f;
        #pragma unroll
        for (int j = 0; j < 64; ++j) s += rsum[j];
        atomicAdd(&S[h], s);
    }
}

// ---------------------------------------------------------------------------
// Kernel E: output projection with deferred softmax normalization.
//   y[d] += sum_v (o[h,v]/S[h]) * Wo[h,v,d]
// grid (16 d-chunks of 256, 32 heads, 2 v-halves), block 256 (4 waves).
// Each wave covers 16 v-rows; float4 loads (1 KB/wave-instr); LDS cross-wave
// reduce; 4 float atomicAdds per surviving thread.
// ---------------------------------------------------------------------------
__global__ void yproj_kernel(const float* __restrict__ Wo,
                             const float* __restrict__ o,
                             const float* __restrict__ S,
                             float* __restrict__ y) {
    const int chunk = blockIdx.x;   // 0..15: 256 d each
    const int h     = blockIdx.y;
    const int vhalf = blockIdx.z;   // 0..1: 64 v each
    const int t     = threadIdx.x;  // 256
    const int wv    = t >> 6;       // wave 0..3
    const int ln    = t & 63;       // lane -> d offset

    __shared__ float s_inv;
    __shared__ float os[V_ / 2];
    if (t == 0) s_inv = 1.f / S[h];
    __syncthreads();
    if (t < 64) os[t] = o[h * V_ + vhalf * 64 + t] * s_inv;
    __syncthreads();

    const int d0 = chunk * 256 + ln * 4;
    const float* Wh = Wo + (size_t)h * V_ * D_ + (size_t)vhalf * 64 * D_;

    f32x4 acc = {0.f, 0.f, 0.f, 0.f};
    const int v0 = wv * 16;
    #pragma unroll
    for (int v = 0; v < 16; ++v)
        acc += os[v0 + v] * ntload4(&Wh[(size_t)(v0 + v) * D_ + d0]);

    __shared__ f32x4 red4[4][64];
    red4[wv][ln] = acc;
    __syncthreads();
    if (t < 64) {
        const f32x4 s = red4[0][t] + red4[1][t] + red4[2][t] + red4[3][t];
        const int d = chunk * 256 + t * 4;
        atomicAdd(&y[d + 0], s.x);
        atomicAdd(&y[d + 1], s.y);
        atomicAdd(&y[d + 2], s.z);
        atomicAdd(&y[d + 3], s.w);
    }
}

// ---------------------------------------------------------------------------
extern "C" void kernel_launch(void* const* d_in, const int* in_sizes, int n_in,
                              void* d_out, int out_size, void* d_ws, size_t ws_size,
                              hipStream_t stream) {
    const float* x      = (const float*)d_in[0];
    const float* prev_K = (const float*)d_in[1];
    const float* prev_V = (const float*)d_in[2];
    const float* Wq     = (const float*)d_in[3];
    const float* Wk     = (const float*)d_in[4];
    const float* Wv     = (const float*)d_in[5];
    const float* Wo     = (const float*)d_in[6];

    float* out = (float*)d_out;
    float* y   = out;                                  // [D]
    float* Kc  = out + D_;                             // [H][MC][K]
    float* Vc  = Kc + (size_t)H_ * MC_ * K_;           // [H][MC][V]

    // workspace (floats): qkv[3][H][K], o[H][V], S[H], mx[H], lg[H][MC]
    float* ws  = (float*)d_ws;
    float* qkv = ws;                                   // 12288
    float* ov  = qkv + 3 * H_ * K_;                    // 4096
    float* Sd  = ov + H_ * V_;                         // 32
    float* mxd = Sd + H_;                              // 32
    float* lg  = mxd + H_;                             // 262144

    // qkv is the only buffer needing pre-zero (proj atomicAdds into it);
    // mx/o/S/y are initialized inside the producer-side kernels.
    hipMemsetAsync(qkv, 0, (size_t)3 * H_ * K_ * sizeof(float), stream);

    proj_kernel        <<<dim3(32, H_, 3), 256, 0, stream>>>(x, Wq, Wk, Wv, qkv, mxd);
    copyK_logits_kernel<<<dim3(128, H_),   256, 0, stream>>>(prev_K, qkv, Kc, lg, mxd, ov, Sd);
    copyV_out_kernel   <<<dim3(128, H_),   256, 0, stream>>>(prev_V, qkv, lg, mxd, Vc, ov, Sd, y);
    yproj_kernel       <<<dim3(16, H_, 2), 256, 0, stream>>>(Wo, ov, Sd, y);
}